// Round 2
// baseline (1990.370 us; speedup 1.0000x reference)
//
#include <hip/hip_runtime.h>
#include <hip/hip_bf16.h>

typedef __bf16 v8bf16 __attribute__((ext_vector_type(8)));
typedef float  v4f32  __attribute__((ext_vector_type(4)));

static __device__ __forceinline__ float leaky(float v) { return v >= 0.0f ? v : 0.01f * v; }

// ---------------------------------------------------------------------------
// Weight transpose+cvt: W[K][N] fp32 -> Wt[N][K] bf16
// ---------------------------------------------------------------------------
__global__ void transpose_cvt(const float* __restrict__ W,
                              __hip_bfloat16* __restrict__ Wt, int K, int N) {
    int i = blockIdx.x * 256 + threadIdx.x;
    if (i >= K * N) return;
    int r = i / N, c = i % N;
    Wt[c * K + r] = __float2bfloat16(W[i]);
}

// ---------------------------------------------------------------------------
// Degree / dinv
// ---------------------------------------------------------------------------
__global__ void deg_init(unsigned* __restrict__ deg, int n) {
    int i = blockIdx.x * 256 + threadIdx.x;
    if (i < n) deg[i] = 1u;  // self-loop
}
__global__ void deg_count(const int* __restrict__ dst, unsigned* __restrict__ deg, int E) {
    int e = blockIdx.x * 256 + threadIdx.x;
    if (e < E) atomicAdd(&deg[dst[e]], 1u);
}
__global__ void dinv_kernel(const unsigned* __restrict__ deg, float* __restrict__ dinv, int n) {
    int i = blockIdx.x * 256 + threadIdx.x;
    if (i < n) dinv[i] = rsqrtf((float)deg[i]);
}

// ---------------------------------------------------------------------------
// GEMM: C[M,N] = A[M,K] @ B[K,N], B pre-transposed+bf16 Bt[N][K].
// One wave: 16 rows x (NT*16) cols via 16x16x32 bf16 MFMA.
// AF32=1: A is fp32 (converted to bf16 in-register). AF32=0: A is bf16.
// MODE 0: Cbf = bf16(leaky(A@B + bias))
// MODE 1: v = (A@B)*dinv[row];  Cf (fp32) = v;  Cbf (bf16 u) = v
// ---------------------------------------------------------------------------
template <int NT, int MODE, int AF32>
__global__ __launch_bounds__(256) void gemm_kernel(
    const void* __restrict__ Avoid, const __hip_bfloat16* __restrict__ Bt,
    const float* __restrict__ bias, const float* __restrict__ dinv,
    __hip_bfloat16* __restrict__ Cbf, float* __restrict__ Cf, int M, int K) {
    const int wid  = threadIdx.x >> 6;
    const int lane = threadIdx.x & 63;
    const int row0 = (blockIdx.x * 4 + wid) << 4;
    if (row0 >= M) return;
    const int m = lane & 15, q = lane >> 4;

    const float*          Af = (const float*)Avoid          + (size_t)(row0 + m) * K + q * 8;
    const __hip_bfloat16* Ab = (const __hip_bfloat16*)Avoid + (size_t)(row0 + m) * K + q * 8;

    v4f32 acc[NT];
#pragma unroll
    for (int t = 0; t < NT; t++) acc[t] = (v4f32){0.f, 0.f, 0.f, 0.f};

    for (int k0 = 0; k0 < K; k0 += 32) {
        v8bf16 a;
        if (AF32) {
            float4 f0 = *reinterpret_cast<const float4*>(Af + k0);
            float4 f1 = *reinterpret_cast<const float4*>(Af + k0 + 4);
            a = (v8bf16){(__bf16)f0.x, (__bf16)f0.y, (__bf16)f0.z, (__bf16)f0.w,
                         (__bf16)f1.x, (__bf16)f1.y, (__bf16)f1.z, (__bf16)f1.w};
        } else {
            a = *reinterpret_cast<const v8bf16*>(Ab + k0);
        }
#pragma unroll
        for (int t = 0; t < NT; t++) {
            v8bf16 b = *reinterpret_cast<const v8bf16*>(Bt + (size_t)(t * 16 + m) * K + k0 + q * 8);
            acc[t] = __builtin_amdgcn_mfma_f32_16x16x32_bf16(a, b, acc[t], 0, 0, 0);
        }
    }

    const int N = NT * 16;
#pragma unroll
    for (int r = 0; r < 4; r++) {
        const int row = row0 + q * 4 + r;
        float di = 1.0f;
        if (MODE == 1) di = dinv[row];
#pragma unroll
        for (int t = 0; t < NT; t++) {
            const int col = t * 16 + m;
            float v = acc[t][r];
            if (MODE == 0) {
                v += bias[col];
                Cbf[(size_t)row * N + col] = __float2bfloat16(leaky(v));
            } else {
                v *= di;
                Cf[(size_t)row * N + col]  = v;
                Cbf[(size_t)row * N + col] = __float2bfloat16(v);
            }
        }
    }
}

// ---------------------------------------------------------------------------
// Edge scatter-add: acc[dst][f] += u[src][f]  — one wave per edge (64 feats)
// ---------------------------------------------------------------------------
__global__ void edge_agg(const int* __restrict__ src, const int* __restrict__ dst,
                         const __hip_bfloat16* __restrict__ u, float* __restrict__ acc,
                         int total) {
    int t = blockIdx.x * 256 + threadIdx.x;
    if (t >= total) return;
    int e = t >> 6, f = t & 63;
    int s = src[e], d = dst[e];
    atomicAdd(&acc[(size_t)d * 64 + f], __bfloat162float(u[(size_t)s * 64 + f]));
}

// ---------------------------------------------------------------------------
// Finalize GCN layer 1: h = bf16(leaky(acc*dinv + bias))
// ---------------------------------------------------------------------------
__global__ void finalize1(const float* __restrict__ acc, const float* __restrict__ dinv,
                          const float* __restrict__ bias,
                          __hip_bfloat16* __restrict__ out, int total) {
    int i = blockIdx.x * 256 + threadIdx.x;
    if (i >= total) return;
    int nidx = i >> 6, f = i & 63;
    float v = acc[i] * dinv[nidx] + bias[f];
    out[i] = __float2bfloat16(leaky(v));
}

// ---------------------------------------------------------------------------
// Finalize GCN2 + classifier head. One wave per node (64 feats in 64 lanes).
// out_h[n] = leaky(acc*dinv + bg2);  logits[n] = out_h[n] @ Wc + bc   (fp32 out)
// ---------------------------------------------------------------------------
__global__ __launch_bounds__(256) void finalize2(
    const float* __restrict__ acc, const float* __restrict__ dinv,
    const float* __restrict__ bias, const float* __restrict__ Wc,
    const float* __restrict__ bc, float* __restrict__ out_logits,
    float* __restrict__ out_h, int n) {
    int node = blockIdx.x * 4 + (threadIdx.x >> 6);
    int f    = threadIdx.x & 63;
    if (node >= n) return;
    float v = acc[(size_t)node * 64 + f] * dinv[node] + bias[f];
    v = leaky(v);
    out_h[(size_t)node * 64 + f] = v;
    float p0 = v * Wc[f * 2 + 0];
    float p1 = v * Wc[f * 2 + 1];
#pragma unroll
    for (int o = 32; o; o >>= 1) {
        p0 += __shfl_xor(p0, o, 64);
        p1 += __shfl_xor(p1, o, 64);
    }
    if (f == 0) {
        out_logits[(size_t)node * 2 + 0] = p0 + bc[0];
        out_logits[(size_t)node * 2 + 1] = p1 + bc[1];
    }
}

// ---------------------------------------------------------------------------
extern "C" void kernel_launch(void* const* d_in, const int* in_sizes, int n_in,
                              void* d_out, int out_size, void* d_ws, size_t ws_size,
                              hipStream_t stream) {
    const float* x   = (const float*)d_in[0];
    const int*   ei  = (const int*)d_in[1];
    const float* W1  = (const float*)d_in[2];
    const float* b1  = (const float*)d_in[3];
    const float* W2  = (const float*)d_in[4];
    const float* b2  = (const float*)d_in[5];
    const float* Wg1 = (const float*)d_in[6];
    const float* bg1 = (const float*)d_in[7];
    const float* Wg2 = (const float*)d_in[8];
    const float* bg2 = (const float*)d_in[9];
    const float* Wc  = (const float*)d_in[10];
    const float* bc  = (const float*)d_in[11];

    const int DH  = in_sizes[3];            // 128
    const int DIN = in_sizes[2] / DH;       // 512
    const int NN  = in_sizes[0] / DIN;      // 100000
    const int E   = in_sizes[1] / 2;        // 3200000
    const int DO  = in_sizes[5];            // 64
    const int* src = ei;
    const int* dst = ei + E;

    // workspace layout
    char*  ws  = (char*)d_ws;
    size_t off = 0;
    auto alloc = [&](size_t bytes) {
        void* p = ws + off;
        off += (bytes + 255) & ~(size_t)255;
        return p;
    };
    __hip_bfloat16* h1   = (__hip_bfloat16*)alloc((size_t)NN * DH * 2);
    __hip_bfloat16* h3   = (__hip_bfloat16*)alloc((size_t)NN * DO * 2);
    __hip_bfloat16* h2   = (__hip_bfloat16*)alloc((size_t)NN * DO * 2);
    __hip_bfloat16* u    = (__hip_bfloat16*)alloc((size_t)NN * DO * 2);
    float*          acc  = (float*)alloc((size_t)NN * DO * 4);
    unsigned*       deg  = (unsigned*)alloc((size_t)NN * 4);
    float*          dinv = (float*)alloc((size_t)NN * 4);
    __hip_bfloat16* W1t  = (__hip_bfloat16*)alloc((size_t)DIN * DH * 2);
    __hip_bfloat16* W2t  = (__hip_bfloat16*)alloc((size_t)DH * DO * 2);
    __hip_bfloat16* Wg1t = (__hip_bfloat16*)alloc((size_t)DO * DO * 2);
    __hip_bfloat16* Wg2t = (__hip_bfloat16*)alloc((size_t)DO * DO * 2);

    float* out_logits = (float*)d_out;
    float* out_h      = (float*)d_out + (size_t)NN * 2;

    // 1. weight transpose + cvt to bf16
    transpose_cvt<<<(DIN * DH + 255) / 256, 256, 0, stream>>>(W1, W1t, DIN, DH);
    transpose_cvt<<<(DH * DO + 255) / 256, 256, 0, stream>>>(W2, W2t, DH, DO);
    transpose_cvt<<<(DO * DO + 255) / 256, 256, 0, stream>>>(Wg1, Wg1t, DO, DO);
    transpose_cvt<<<(DO * DO + 255) / 256, 256, 0, stream>>>(Wg2, Wg2t, DO, DO);

    // 2. degrees
    deg_init<<<(NN + 255) / 256, 256, 0, stream>>>(deg, NN);
    deg_count<<<(E + 255) / 256, 256, 0, stream>>>(dst, deg, E);
    dinv_kernel<<<(NN + 255) / 256, 256, 0, stream>>>(deg, dinv, NN);

    const int gemm_blocks = (NN / 16 + 3) / 4;

    // 3. encoder (x is fp32 -> AF32=1; later GEMMs read bf16 intermediates)
    gemm_kernel<8, 0, 1><<<gemm_blocks, 256, 0, stream>>>(x, W1t, b1, nullptr, h1, nullptr, NN, DIN);
    gemm_kernel<4, 0, 0><<<gemm_blocks, 256, 0, stream>>>(h1, W2t, b2, nullptr, h2, nullptr, NN, DH);

    // 4. GCN layer 1
    gemm_kernel<4, 1, 0><<<gemm_blocks, 256, 0, stream>>>(h2, Wg1t, nullptr, dinv, u, acc, NN, DO);
    edge_agg<<<(E * 64 + 255) / 256, 256, 0, stream>>>(src, dst, u, acc, E * 64);
    finalize1<<<(NN * 64 + 255) / 256, 256, 0, stream>>>(acc, dinv, bg1, h3, NN * 64);

    // 5. GCN layer 2
    gemm_kernel<4, 1, 0><<<gemm_blocks, 256, 0, stream>>>(h3, Wg2t, nullptr, dinv, u, acc, NN, DO);
    edge_agg<<<(E * 64 + 255) / 256, 256, 0, stream>>>(src, dst, u, acc, E * 64);

    // 6. finalize + head (fp32 outputs)
    finalize2<<<(NN + 3) / 4, 256, 0, stream>>>(acc, dinv, bg2, Wc, bc, out_logits, out_h, NN);
}

// Round 3
// 1064.695 us; speedup vs baseline: 1.8694x; 1.8694x over previous
//
#include <hip/hip_runtime.h>
#include <hip/hip_bf16.h>

typedef __bf16 v8bf16 __attribute__((ext_vector_type(8)));
typedef float  v4f32  __attribute__((ext_vector_type(4)));

static __device__ __forceinline__ float leaky(float v) { return v >= 0.0f ? v : 0.01f * v; }
static __device__ __forceinline__ float bfbits2f(unsigned short b) {
    union { unsigned u; float f; } c; c.u = ((unsigned)b) << 16; return c.f;
}
static __device__ __forceinline__ unsigned short f2bfbits(float f) {
    __hip_bfloat16 h = __float2bfloat16(f);
    unsigned short s; __builtin_memcpy(&s, &h, 2); return s;
}

// ---------------------------------------------------------------------------
// Weight transpose+cvt: W[K][N] fp32 -> Wt[N][K] bf16
// ---------------------------------------------------------------------------
__global__ void transpose_cvt(const float* __restrict__ W,
                              __hip_bfloat16* __restrict__ Wt, int K, int N) {
    int i = blockIdx.x * 256 + threadIdx.x;
    if (i >= K * N) return;
    int r = i / N, c = i % N;
    Wt[c * K + r] = __float2bfloat16(W[i]);
}

// ---------------------------------------------------------------------------
// CSR build: histogram -> scan -> placement
// ---------------------------------------------------------------------------
__global__ void zero_u32(unsigned* __restrict__ p, int n) {
    int i = blockIdx.x * 256 + threadIdx.x;
    if (i < n) p[i] = 0u;
}
__global__ void deg_count(const int* __restrict__ dst, unsigned* __restrict__ deg, int E) {
    int e = blockIdx.x * 256 + threadIdx.x;
    if (e < E) atomicAdd(&deg[dst[e]], 1u);
}
__global__ void dinv_kernel(const unsigned* __restrict__ deg, float* __restrict__ dinv, int n) {
    int i = blockIdx.x * 256 + threadIdx.x;
    if (i < n) dinv[i] = rsqrtf((float)(deg[i] + 1u));  // +1 self-loop
}

// scan1: per-block (1024 elems = 256 thr x 4) inclusive scan + block totals
__global__ __launch_bounds__(256) void scan1(const unsigned* __restrict__ in,
                                             unsigned* __restrict__ incl,
                                             unsigned* __restrict__ partials, int n) {
    __shared__ unsigned ts[256];
    const int tid = threadIdx.x;
    const int base = blockIdx.x * 1024 + tid * 4;
    unsigned v[4], s = 0;
#pragma unroll
    for (int j = 0; j < 4; j++) { v[j] = (base + j < n) ? in[base + j] : 0u; s += v[j]; }
    ts[tid] = s;
    __syncthreads();
    for (int off = 1; off < 256; off <<= 1) {
        unsigned t = (tid >= off) ? ts[tid - off] : 0u;
        __syncthreads();
        ts[tid] += t;
        __syncthreads();
    }
    unsigned run = ts[tid] - s;  // exclusive for this thread
#pragma unroll
    for (int j = 0; j < 4; j++) {
        run += v[j];
        if (base + j < n) incl[base + j] = run;
    }
    if (tid == 255) partials[blockIdx.x] = ts[255];
}

// scan2: single block, exclusive-scan the block totals (nb <= 128)
__global__ __launch_bounds__(128) void scan2(unsigned* __restrict__ partials, int nb) {
    __shared__ unsigned ts[128];
    const int tid = threadIdx.x;
    unsigned v = (tid < nb) ? partials[tid] : 0u;
    ts[tid] = v;
    __syncthreads();
    for (int off = 1; off < 128; off <<= 1) {
        unsigned t = (tid >= off) ? ts[tid - off] : 0u;
        __syncthreads();
        ts[tid] += t;
        __syncthreads();
    }
    if (tid < nb) partials[tid] = ts[tid] - v;  // exclusive
}

// scan3: rowptr[i+1] = incl[i] + partials[i/1024]; rowptr[0]=0; cursor[i]=rowptr[i]
__global__ void scan3(const unsigned* __restrict__ incl, const unsigned* __restrict__ partials,
                      const unsigned* __restrict__ deg, unsigned* __restrict__ rowptr,
                      unsigned* __restrict__ cursor, int n) {
    int i = blockIdx.x * 256 + threadIdx.x;
    if (i >= n) return;
    unsigned val = incl[i] + partials[i >> 10];
    rowptr[i + 1] = val;
    cursor[i] = val - deg[i];
    if (i == 0) rowptr[0] = 0u;
}

__global__ void fill_csr(const int* __restrict__ src, const int* __restrict__ dst,
                         unsigned* __restrict__ cursor, int* __restrict__ csr_src, int E) {
    int e = blockIdx.x * 256 + threadIdx.x;
    if (e >= E) return;
    unsigned pos = atomicAdd(&cursor[dst[e]], 1u);
    csr_src[pos] = src[e];
}

// ---------------------------------------------------------------------------
// GEMM: C[M,N] = A[M,K] @ B[K,N], B pre-transposed+bf16 Bt[N][K].
// One wave: 16 rows x (NT*16) cols via 16x16x32 bf16 MFMA.
// AF32=1: A fp32 (cvt in-register). MODE 0: C=bf16(leaky(AB+bias));
// MODE 1: C=bf16((AB)*dinv[row])
// ---------------------------------------------------------------------------
template <int NT, int MODE, int AF32>
__global__ __launch_bounds__(256) void gemm_kernel(
    const void* __restrict__ Avoid, const __hip_bfloat16* __restrict__ Bt,
    const float* __restrict__ bias, const float* __restrict__ dinv,
    __hip_bfloat16* __restrict__ Cbf, int M, int K) {
    const int wid  = threadIdx.x >> 6;
    const int lane = threadIdx.x & 63;
    const int row0 = (blockIdx.x * 4 + wid) << 4;
    if (row0 >= M) return;
    const int m = lane & 15, q = lane >> 4;

    const float*          Af = (const float*)Avoid          + (size_t)(row0 + m) * K + q * 8;
    const __hip_bfloat16* Ab = (const __hip_bfloat16*)Avoid + (size_t)(row0 + m) * K + q * 8;

    v4f32 acc[NT];
#pragma unroll
    for (int t = 0; t < NT; t++) acc[t] = (v4f32){0.f, 0.f, 0.f, 0.f};

    for (int k0 = 0; k0 < K; k0 += 32) {
        v8bf16 a;
        if (AF32) {
            float4 f0 = *reinterpret_cast<const float4*>(Af + k0);
            float4 f1 = *reinterpret_cast<const float4*>(Af + k0 + 4);
            a = (v8bf16){(__bf16)f0.x, (__bf16)f0.y, (__bf16)f0.z, (__bf16)f0.w,
                         (__bf16)f1.x, (__bf16)f1.y, (__bf16)f1.z, (__bf16)f1.w};
        } else {
            a = *reinterpret_cast<const v8bf16*>(Ab + k0);
        }
#pragma unroll
        for (int t = 0; t < NT; t++) {
            v8bf16 b = *reinterpret_cast<const v8bf16*>(Bt + (size_t)(t * 16 + m) * K + k0 + q * 8);
            acc[t] = __builtin_amdgcn_mfma_f32_16x16x32_bf16(a, b, acc[t], 0, 0, 0);
        }
    }

    const int N = NT * 16;
#pragma unroll
    for (int r = 0; r < 4; r++) {
        const int row = row0 + q * 4 + r;
        float di = (MODE == 1) ? dinv[row] : 1.0f;
#pragma unroll
        for (int t = 0; t < NT; t++) {
            const int col = t * 16 + m;
            float v = acc[t][r];
            if (MODE == 0) v = leaky(v + bias[col]);
            else           v *= di;
            Cbf[(size_t)row * N + col] = __float2bfloat16(v);
        }
    }
}

// ---------------------------------------------------------------------------
// Fused CSR gather + GCN epilogue. One wave per dst node.
// Lane (g = lane>>4, t = lane&15): g picks edge slot, t picks feature quad.
// Per iter: 4 edges, each a 128 B coalesced bf16 row read.
// out = leaky(dinv[n] * (u[n] + sum_{src} u[src]) + bias)
// HEAD=0: write bf16 h. HEAD=1: write fp32 h + logits = h @ Wc + bc.
// ---------------------------------------------------------------------------
template <int HEAD>
__global__ __launch_bounds__(256) void gather_kernel(
    const unsigned* __restrict__ rowptr, const int* __restrict__ csr_src,
    const __hip_bfloat16* __restrict__ u, const float* __restrict__ dinv,
    const float* __restrict__ bias, __hip_bfloat16* __restrict__ out_bf,
    float* __restrict__ out_h, const float* __restrict__ Wc,
    const float* __restrict__ bc, float* __restrict__ out_logits, int n) {
    const int node = blockIdx.x * 4 + (threadIdx.x >> 6);
    if (node >= n) return;
    const int lane = threadIdx.x & 63;
    const int g = lane >> 4, t = lane & 15;
    const unsigned beg = rowptr[node], end = rowptr[node + 1];

    float s0 = 0.f, s1 = 0.f, s2 = 0.f, s3 = 0.f;
    for (unsigned e = beg + g; e < end; e += 4) {
        int sidx = csr_src[e];
        ushort4 w = *reinterpret_cast<const ushort4*>(u + (size_t)sidx * 64 + t * 4);
        s0 += bfbits2f(w.x); s1 += bfbits2f(w.y); s2 += bfbits2f(w.z); s3 += bfbits2f(w.w);
    }
    // combine the 4 edge-slot groups (lanes differing in bits 4,5)
    s0 += __shfl_xor(s0, 16, 64); s1 += __shfl_xor(s1, 16, 64);
    s2 += __shfl_xor(s2, 16, 64); s3 += __shfl_xor(s3, 16, 64);
    s0 += __shfl_xor(s0, 32, 64); s1 += __shfl_xor(s1, 32, 64);
    s2 += __shfl_xor(s2, 32, 64); s3 += __shfl_xor(s3, 32, 64);

    // self-loop term
    ushort4 ws = *reinterpret_cast<const ushort4*>(u + (size_t)node * 64 + t * 4);
    s0 += bfbits2f(ws.x); s1 += bfbits2f(ws.y); s2 += bfbits2f(ws.z); s3 += bfbits2f(ws.w);

    const float di = dinv[node];
    const int f0i = t * 4;
    float f0 = leaky(s0 * di + bias[f0i + 0]);
    float f1 = leaky(s1 * di + bias[f0i + 1]);
    float f2 = leaky(s2 * di + bias[f0i + 2]);
    float f3 = leaky(s3 * di + bias[f0i + 3]);

    if (HEAD == 0) {
        if (g == 0) {
            ushort4 o = {f2bfbits(f0), f2bfbits(f1), f2bfbits(f2), f2bfbits(f3)};
            *reinterpret_cast<ushort4*>(out_bf + (size_t)node * 64 + f0i) = o;
        }
    } else {
        if (g == 0) {
            float4 o = {f0, f1, f2, f3};
            *reinterpret_cast<float4*>(out_h + (size_t)node * 64 + f0i) = o;
        }
        float p0 = f0 * Wc[(f0i + 0) * 2] + f1 * Wc[(f0i + 1) * 2] +
                   f2 * Wc[(f0i + 2) * 2] + f3 * Wc[(f0i + 3) * 2];
        float p1 = f0 * Wc[(f0i + 0) * 2 + 1] + f1 * Wc[(f0i + 1) * 2 + 1] +
                   f2 * Wc[(f0i + 2) * 2 + 1] + f3 * Wc[(f0i + 3) * 2 + 1];
#pragma unroll
        for (int o = 8; o; o >>= 1) {
            p0 += __shfl_xor(p0, o, 64);
            p1 += __shfl_xor(p1, o, 64);
        }
        if (lane == 0) {
            out_logits[(size_t)node * 2 + 0] = p0 + bc[0];
            out_logits[(size_t)node * 2 + 1] = p1 + bc[1];
        }
    }
}

// ---------------------------------------------------------------------------
extern "C" void kernel_launch(void* const* d_in, const int* in_sizes, int n_in,
                              void* d_out, int out_size, void* d_ws, size_t ws_size,
                              hipStream_t stream) {
    const float* x   = (const float*)d_in[0];
    const int*   ei  = (const int*)d_in[1];
    const float* W1  = (const float*)d_in[2];
    const float* b1  = (const float*)d_in[3];
    const float* W2  = (const float*)d_in[4];
    const float* b2  = (const float*)d_in[5];
    const float* Wg1 = (const float*)d_in[6];
    const float* bg1 = (const float*)d_in[7];
    const float* Wg2 = (const float*)d_in[8];
    const float* bg2 = (const float*)d_in[9];
    const float* Wc  = (const float*)d_in[10];
    const float* bc  = (const float*)d_in[11];

    const int DH  = in_sizes[3];            // 128
    const int DIN = in_sizes[2] / DH;       // 512
    const int NN  = in_sizes[0] / DIN;      // 100000
    const int E   = in_sizes[1] / 2;        // 3200000
    const int DO  = in_sizes[5];            // 64
    const int* src = ei;
    const int* dst = ei + E;

    // workspace layout (~79 MB total)
    char*  ws  = (char*)d_ws;
    size_t off = 0;
    auto alloc = [&](size_t bytes) {
        void* p = ws + off;
        off += (bytes + 255) & ~(size_t)255;
        return p;
    };
    __hip_bfloat16* h1    = (__hip_bfloat16*)alloc((size_t)NN * DH * 2);
    __hip_bfloat16* h2    = (__hip_bfloat16*)alloc((size_t)NN * DO * 2);
    __hip_bfloat16* h3    = (__hip_bfloat16*)alloc((size_t)NN * DO * 2);
    __hip_bfloat16* ub    = (__hip_bfloat16*)alloc((size_t)NN * DO * 2);
    unsigned*       deg   = (unsigned*)alloc((size_t)NN * 4);
    float*          dinv  = (float*)alloc((size_t)NN * 4);
    unsigned*       incl  = (unsigned*)alloc((size_t)NN * 4);
    unsigned*       parts = (unsigned*)alloc(128 * 4);
    unsigned*       rowp  = (unsigned*)alloc(((size_t)NN + 1) * 4);
    unsigned*       curs  = (unsigned*)alloc((size_t)NN * 4);
    int*            csr   = (int*)alloc((size_t)E * 4);
    __hip_bfloat16* W1t   = (__hip_bfloat16*)alloc((size_t)DIN * DH * 2);
    __hip_bfloat16* W2t   = (__hip_bfloat16*)alloc((size_t)DH * DO * 2);
    __hip_bfloat16* Wg1t  = (__hip_bfloat16*)alloc((size_t)DO * DO * 2);
    __hip_bfloat16* Wg2t  = (__hip_bfloat16*)alloc((size_t)DO * DO * 2);

    float* out_logits = (float*)d_out;
    float* out_h      = (float*)d_out + (size_t)NN * 2;

    // 1. weights -> transposed bf16
    transpose_cvt<<<(DIN * DH + 255) / 256, 256, 0, stream>>>(W1, W1t, DIN, DH);
    transpose_cvt<<<(DH * DO + 255) / 256, 256, 0, stream>>>(W2, W2t, DH, DO);
    transpose_cvt<<<(DO * DO + 255) / 256, 256, 0, stream>>>(Wg1, Wg1t, DO, DO);
    transpose_cvt<<<(DO * DO + 255) / 256, 256, 0, stream>>>(Wg2, Wg2t, DO, DO);

    // 2. CSR build (shared by both GCN layers)
    zero_u32<<<(NN + 255) / 256, 256, 0, stream>>>(deg, NN);
    deg_count<<<(E + 255) / 256, 256, 0, stream>>>(dst, deg, E);
    dinv_kernel<<<(NN + 255) / 256, 256, 0, stream>>>(deg, dinv, NN);
    const int nb1 = (NN + 1023) / 1024;  // 98 <= 128
    scan1<<<nb1, 256, 0, stream>>>(deg, incl, parts, NN);
    scan2<<<1, 128, 0, stream>>>(parts, nb1);
    scan3<<<(NN + 255) / 256, 256, 0, stream>>>(incl, parts, deg, rowp, curs, NN);
    fill_csr<<<(E + 255) / 256, 256, 0, stream>>>(src, dst, curs, csr, E);

    const int gemm_blocks = (NN / 16 + 3) / 4;

    // 3. encoder
    gemm_kernel<8, 0, 1><<<gemm_blocks, 256, 0, stream>>>(x, W1t, b1, nullptr, h1, NN, DIN);
    gemm_kernel<4, 0, 0><<<gemm_blocks, 256, 0, stream>>>(h1, W2t, b2, nullptr, h2, NN, DH);

    // 4. GCN layer 1: u = (h2@Wg1)*dinv ; gather ; epilogue -> h3 (bf16)
    gemm_kernel<4, 1, 0><<<gemm_blocks, 256, 0, stream>>>(h2, Wg1t, nullptr, dinv, ub, NN, DO);
    gather_kernel<0><<<(NN + 3) / 4, 256, 0, stream>>>(rowp, csr, ub, dinv, bg1, h3,
                                                       nullptr, nullptr, nullptr, nullptr, NN);

    // 5. GCN layer 2 + head
    gemm_kernel<4, 1, 0><<<gemm_blocks, 256, 0, stream>>>(h3, Wg2t, nullptr, dinv, ub, NN, DO);
    gather_kernel<1><<<(NN + 3) / 4, 256, 0, stream>>>(rowp, csr, ub, dinv, bg2, nullptr,
                                                       out_h, Wc, bc, out_logits, NN);
}

// Round 4
// 855.931 us; speedup vs baseline: 2.3254x; 1.2439x over previous
//
#include <hip/hip_runtime.h>
#include <hip/hip_bf16.h>

typedef __bf16 v8bf16 __attribute__((ext_vector_type(8)));
typedef float  v4f32  __attribute__((ext_vector_type(4)));

static __device__ __forceinline__ float leaky(float v) { return v >= 0.0f ? v : 0.01f * v; }
static __device__ __forceinline__ float bfbits2f(unsigned short b) {
    union { unsigned u; float f; } c; c.u = ((unsigned)b) << 16; return c.f;
}
static __device__ __forceinline__ unsigned short f2bfbits(float f) {
    __hip_bfloat16 h = __float2bfloat16(f);
    unsigned short s; __builtin_memcpy(&s, &h, 2); return s;
}

// ---------------------------------------------------------------------------
// Weight transpose+cvt: W[K][N] fp32 -> Wt[N][K] bf16
// ---------------------------------------------------------------------------
__global__ void transpose_cvt(const float* __restrict__ W,
                              __hip_bfloat16* __restrict__ Wt, int K, int N) {
    int i = blockIdx.x * 256 + threadIdx.x;
    if (i >= K * N) return;
    int r = i / N, c = i % N;
    Wt[c * K + r] = __float2bfloat16(W[i]);
}

// ---------------------------------------------------------------------------
// CSR build: histogram(+rank) -> scan -> atomic-free placement
// ---------------------------------------------------------------------------
__global__ void zero_u32(unsigned* __restrict__ p, int n) {
    int i = blockIdx.x * 256 + threadIdx.x;
    if (i < n) p[i] = 0u;
}
// rank[e] = old count of dst[e]; deg[d] ends as in-degree of d
__global__ void deg_rank(const int* __restrict__ dst, unsigned* __restrict__ deg,
                         unsigned* __restrict__ rank, int E) {
    int e = blockIdx.x * 256 + threadIdx.x;
    if (e < E) rank[e] = atomicAdd(&deg[dst[e]], 1u);
}
__global__ void dinv_kernel(const unsigned* __restrict__ deg, float* __restrict__ dinv, int n) {
    int i = blockIdx.x * 256 + threadIdx.x;
    if (i < n) dinv[i] = rsqrtf((float)(deg[i] + 1u));  // +1 self-loop
}

// scan1: per-block (1024 elems = 256 thr x 4) inclusive scan + block totals
__global__ __launch_bounds__(256) void scan1(const unsigned* __restrict__ in,
                                             unsigned* __restrict__ incl,
                                             unsigned* __restrict__ partials, int n) {
    __shared__ unsigned ts[256];
    const int tid = threadIdx.x;
    const int base = blockIdx.x * 1024 + tid * 4;
    unsigned v[4], s = 0;
#pragma unroll
    for (int j = 0; j < 4; j++) { v[j] = (base + j < n) ? in[base + j] : 0u; s += v[j]; }
    ts[tid] = s;
    __syncthreads();
    for (int off = 1; off < 256; off <<= 1) {
        unsigned t = (tid >= off) ? ts[tid - off] : 0u;
        __syncthreads();
        ts[tid] += t;
        __syncthreads();
    }
    unsigned run = ts[tid] - s;  // exclusive for this thread
#pragma unroll
    for (int j = 0; j < 4; j++) {
        run += v[j];
        if (base + j < n) incl[base + j] = run;
    }
    if (tid == 255) partials[blockIdx.x] = ts[255];
}

// scan2: single block, exclusive-scan the block totals (nb <= 128)
__global__ __launch_bounds__(128) void scan2(unsigned* __restrict__ partials, int nb) {
    __shared__ unsigned ts[128];
    const int tid = threadIdx.x;
    unsigned v = (tid < nb) ? partials[tid] : 0u;
    ts[tid] = v;
    __syncthreads();
    for (int off = 1; off < 128; off <<= 1) {
        unsigned t = (tid >= off) ? ts[tid - off] : 0u;
        __syncthreads();
        ts[tid] += t;
        __syncthreads();
    }
    if (tid < nb) partials[tid] = ts[tid] - v;  // exclusive
}

// scan3: rowptr[i+1] = incl[i] + partials[i/1024]; rowptr[0]=0
__global__ void scan3(const unsigned* __restrict__ incl, const unsigned* __restrict__ partials,
                      unsigned* __restrict__ rowptr, int n) {
    int i = blockIdx.x * 256 + threadIdx.x;
    if (i >= n) return;
    rowptr[i + 1] = incl[i] + partials[i >> 10];
    if (i == 0) rowptr[0] = 0u;
}

// atomic-free placement: pos = rowptr[dst] + rank  (1 random store per edge)
__global__ void fill_csr(const int* __restrict__ src, const int* __restrict__ dst,
                         const unsigned* __restrict__ rank, const unsigned* __restrict__ rowptr,
                         int* __restrict__ csr_src, int E) {
    int e = blockIdx.x * 256 + threadIdx.x;
    if (e >= E) return;
    csr_src[rowptr[dst[e]] + rank[e]] = src[e];
}

// ---------------------------------------------------------------------------
// GEMM: C[M,N] = A[M,K] @ B[K,N], B pre-transposed+bf16 Bt[N][K].
// One wave: 16 rows x (NT*16) cols via 16x16x32 bf16 MFMA.
// AF32=1: A fp32 (cvt in-register). MODE 0: C=bf16(leaky(AB+bias));
// MODE 1: C=bf16((AB)*dinv[row])
// ---------------------------------------------------------------------------
template <int NT, int MODE, int AF32>
__global__ __launch_bounds__(256) void gemm_kernel(
    const void* __restrict__ Avoid, const __hip_bfloat16* __restrict__ Bt,
    const float* __restrict__ bias, const float* __restrict__ dinv,
    __hip_bfloat16* __restrict__ Cbf, int M, int K) {
    const int wid  = threadIdx.x >> 6;
    const int lane = threadIdx.x & 63;
    const int row0 = (blockIdx.x * 4 + wid) << 4;
    if (row0 >= M) return;
    const int m = lane & 15, q = lane >> 4;

    const float*          Af = (const float*)Avoid          + (size_t)(row0 + m) * K + q * 8;
    const __hip_bfloat16* Ab = (const __hip_bfloat16*)Avoid + (size_t)(row0 + m) * K + q * 8;

    v4f32 acc[NT];
#pragma unroll
    for (int t = 0; t < NT; t++) acc[t] = (v4f32){0.f, 0.f, 0.f, 0.f};

    for (int k0 = 0; k0 < K; k0 += 32) {
        v8bf16 a;
        if (AF32) {
            float4 f0 = *reinterpret_cast<const float4*>(Af + k0);
            float4 f1 = *reinterpret_cast<const float4*>(Af + k0 + 4);
            a = (v8bf16){(__bf16)f0.x, (__bf16)f0.y, (__bf16)f0.z, (__bf16)f0.w,
                         (__bf16)f1.x, (__bf16)f1.y, (__bf16)f1.z, (__bf16)f1.w};
        } else {
            a = *reinterpret_cast<const v8bf16*>(Ab + k0);
        }
#pragma unroll
        for (int t = 0; t < NT; t++) {
            v8bf16 b = *reinterpret_cast<const v8bf16*>(Bt + (size_t)(t * 16 + m) * K + k0 + q * 8);
            acc[t] = __builtin_amdgcn_mfma_f32_16x16x32_bf16(a, b, acc[t], 0, 0, 0);
        }
    }

    const int N = NT * 16;
#pragma unroll
    for (int r = 0; r < 4; r++) {
        const int row = row0 + q * 4 + r;
        float di = (MODE == 1) ? dinv[row] : 1.0f;
#pragma unroll
        for (int t = 0; t < NT; t++) {
            const int col = t * 16 + m;
            float v = acc[t][r];
            if (MODE == 0) v = leaky(v + bias[col]);
            else           v *= di;
            Cbf[(size_t)row * N + col] = __float2bfloat16(v);
        }
    }
}

// ---------------------------------------------------------------------------
// Fused CSR gather + GCN epilogue. One wave per dst node.
// Lane (g = lane>>4, t = lane&15): g picks edge slot, t picks feature quad.
// out = leaky(dinv[n] * (u[n] + sum_{src} u[src]) + bias)
// HEAD=0: write bf16 h. HEAD=1: write fp32 h + logits = h @ Wc + bc.
// ---------------------------------------------------------------------------
template <int HEAD>
__global__ __launch_bounds__(256) void gather_kernel(
    const unsigned* __restrict__ rowptr, const int* __restrict__ csr_src,
    const __hip_bfloat16* __restrict__ u, const float* __restrict__ dinv,
    const float* __restrict__ bias, __hip_bfloat16* __restrict__ out_bf,
    float* __restrict__ out_h, const float* __restrict__ Wc,
    const float* __restrict__ bc, float* __restrict__ out_logits, int n) {
    const int node = blockIdx.x * 4 + (threadIdx.x >> 6);
    if (node >= n) return;
    const int lane = threadIdx.x & 63;
    const int g = lane >> 4, t = lane & 15;
    const unsigned beg = rowptr[node], end = rowptr[node + 1];

    float s0 = 0.f, s1 = 0.f, s2 = 0.f, s3 = 0.f;
    for (unsigned e = beg + g; e < end; e += 4) {
        int sidx = csr_src[e];
        ushort4 w = *reinterpret_cast<const ushort4*>(u + (size_t)sidx * 64 + t * 4);
        s0 += bfbits2f(w.x); s1 += bfbits2f(w.y); s2 += bfbits2f(w.z); s3 += bfbits2f(w.w);
    }
    // combine the 4 edge-slot groups (lanes differing in bits 4,5)
    s0 += __shfl_xor(s0, 16, 64); s1 += __shfl_xor(s1, 16, 64);
    s2 += __shfl_xor(s2, 16, 64); s3 += __shfl_xor(s3, 16, 64);
    s0 += __shfl_xor(s0, 32, 64); s1 += __shfl_xor(s1, 32, 64);
    s2 += __shfl_xor(s2, 32, 64); s3 += __shfl_xor(s3, 32, 64);

    // self-loop term
    ushort4 ws = *reinterpret_cast<const ushort4*>(u + (size_t)node * 64 + t * 4);
    s0 += bfbits2f(ws.x); s1 += bfbits2f(ws.y); s2 += bfbits2f(ws.z); s3 += bfbits2f(ws.w);

    const float di = dinv[node];
    const int f0i = t * 4;
    float f0 = leaky(s0 * di + bias[f0i + 0]);
    float f1 = leaky(s1 * di + bias[f0i + 1]);
    float f2 = leaky(s2 * di + bias[f0i + 2]);
    float f3 = leaky(s3 * di + bias[f0i + 3]);

    if (HEAD == 0) {
        if (g == 0) {
            ushort4 o = {f2bfbits(f0), f2bfbits(f1), f2bfbits(f2), f2bfbits(f3)};
            *reinterpret_cast<ushort4*>(out_bf + (size_t)node * 64 + f0i) = o;
        }
    } else {
        if (g == 0) {
            float4 o = {f0, f1, f2, f3};
            *reinterpret_cast<float4*>(out_h + (size_t)node * 64 + f0i) = o;
        }
        float p0 = f0 * Wc[(f0i + 0) * 2] + f1 * Wc[(f0i + 1) * 2] +
                   f2 * Wc[(f0i + 2) * 2] + f3 * Wc[(f0i + 3) * 2];
        float p1 = f0 * Wc[(f0i + 0) * 2 + 1] + f1 * Wc[(f0i + 1) * 2 + 1] +
                   f2 * Wc[(f0i + 2) * 2 + 1] + f3 * Wc[(f0i + 3) * 2 + 1];
#pragma unroll
        for (int o = 8; o; o >>= 1) {
            p0 += __shfl_xor(p0, o, 64);
            p1 += __shfl_xor(p1, o, 64);
        }
        if (lane == 0) {
            out_logits[(size_t)node * 2 + 0] = p0 + bc[0];
            out_logits[(size_t)node * 2 + 1] = p1 + bc[1];
        }
    }
}

// ---------------------------------------------------------------------------
extern "C" void kernel_launch(void* const* d_in, const int* in_sizes, int n_in,
                              void* d_out, int out_size, void* d_ws, size_t ws_size,
                              hipStream_t stream) {
    const float* x   = (const float*)d_in[0];
    const int*   ei  = (const int*)d_in[1];
    const float* W1  = (const float*)d_in[2];
    const float* b1  = (const float*)d_in[3];
    const float* W2  = (const float*)d_in[4];
    const float* b2  = (const float*)d_in[5];
    const float* Wg1 = (const float*)d_in[6];
    const float* bg1 = (const float*)d_in[7];
    const float* Wg2 = (const float*)d_in[8];
    const float* bg2 = (const float*)d_in[9];
    const float* Wc  = (const float*)d_in[10];
    const float* bc  = (const float*)d_in[11];

    const int DH  = in_sizes[3];            // 128
    const int DIN = in_sizes[2] / DH;       // 512
    const int NN  = in_sizes[0] / DIN;      // 100000
    const int E   = in_sizes[1] / 2;        // 3200000
    const int DO  = in_sizes[5];            // 64
    const int* src = ei;
    const int* dst = ei + E;

    // workspace layout (~92 MB total)
    char*  ws  = (char*)d_ws;
    size_t off = 0;
    auto alloc = [&](size_t bytes) {
        void* p = ws + off;
        off += (bytes + 255) & ~(size_t)255;
        return p;
    };
    __hip_bfloat16* h1    = (__hip_bfloat16*)alloc((size_t)NN * DH * 2);
    __hip_bfloat16* h2    = (__hip_bfloat16*)alloc((size_t)NN * DO * 2);
    __hip_bfloat16* h3    = (__hip_bfloat16*)alloc((size_t)NN * DO * 2);
    __hip_bfloat16* ub    = (__hip_bfloat16*)alloc((size_t)NN * DO * 2);
    unsigned*       deg   = (unsigned*)alloc((size_t)NN * 4);
    float*          dinv  = (float*)alloc((size_t)NN * 4);
    unsigned*       incl  = (unsigned*)alloc((size_t)NN * 4);
    unsigned*       parts = (unsigned*)alloc(128 * 4);
    unsigned*       rowp  = (unsigned*)alloc(((size_t)NN + 1) * 4);
    unsigned*       rank  = (unsigned*)alloc((size_t)E * 4);
    int*            csr   = (int*)alloc((size_t)E * 4);
    __hip_bfloat16* W1t   = (__hip_bfloat16*)alloc((size_t)DIN * DH * 2);
    __hip_bfloat16* W2t   = (__hip_bfloat16*)alloc((size_t)DH * DO * 2);
    __hip_bfloat16* Wg1t  = (__hip_bfloat16*)alloc((size_t)DO * DO * 2);
    __hip_bfloat16* Wg2t  = (__hip_bfloat16*)alloc((size_t)DO * DO * 2);

    float* out_logits = (float*)d_out;
    float* out_h      = (float*)d_out + (size_t)NN * 2;

    // 1. weights -> transposed bf16
    transpose_cvt<<<(DIN * DH + 255) / 256, 256, 0, stream>>>(W1, W1t, DIN, DH);
    transpose_cvt<<<(DH * DO + 255) / 256, 256, 0, stream>>>(W2, W2t, DH, DO);
    transpose_cvt<<<(DO * DO + 255) / 256, 256, 0, stream>>>(Wg1, Wg1t, DO, DO);
    transpose_cvt<<<(DO * DO + 255) / 256, 256, 0, stream>>>(Wg2, Wg2t, DO, DO);

    // 2. CSR build (shared by both GCN layers)
    zero_u32<<<(NN + 255) / 256, 256, 0, stream>>>(deg, NN);
    deg_rank<<<(E + 255) / 256, 256, 0, stream>>>(dst, deg, rank, E);
    dinv_kernel<<<(NN + 255) / 256, 256, 0, stream>>>(deg, dinv, NN);
    const int nb1 = (NN + 1023) / 1024;  // 98 <= 128
    scan1<<<nb1, 256, 0, stream>>>(deg, incl, parts, NN);
    scan2<<<1, 128, 0, stream>>>(parts, nb1);
    scan3<<<(NN + 255) / 256, 256, 0, stream>>>(incl, parts, rowp, NN);
    fill_csr<<<(E + 255) / 256, 256, 0, stream>>>(src, dst, rank, rowp, csr, E);

    const int gemm_blocks = (NN / 16 + 3) / 4;

    // 3. encoder
    gemm_kernel<8, 0, 1><<<gemm_blocks, 256, 0, stream>>>(x, W1t, b1, nullptr, h1, NN, DIN);
    gemm_kernel<4, 0, 0><<<gemm_blocks, 256, 0, stream>>>(h1, W2t, b2, nullptr, h2, NN, DH);

    // 4. GCN layer 1: u = (h2@Wg1)*dinv ; gather ; epilogue -> h3 (bf16)
    gemm_kernel<4, 1, 0><<<gemm_blocks, 256, 0, stream>>>(h2, Wg1t, nullptr, dinv, ub, NN, DO);
    gather_kernel<0><<<(NN + 3) / 4, 256, 0, stream>>>(rowp, csr, ub, dinv, bg1, h3,
                                                       nullptr, nullptr, nullptr, nullptr, NN);

    // 5. GCN layer 2 + head
    gemm_kernel<4, 1, 0><<<gemm_blocks, 256, 0, stream>>>(h3, Wg2t, nullptr, dinv, ub, NN, DO);
    gather_kernel<1><<<(NN + 3) / 4, 256, 0, stream>>>(rowp, csr, ub, dinv, bg2, nullptr,
                                                       out_h, Wc, bc, out_logits, NN);
}

// Round 5
// 792.013 us; speedup vs baseline: 2.5131x; 1.0807x over previous
//
#include <hip/hip_runtime.h>
#include <hip/hip_bf16.h>

typedef __bf16 v8bf16 __attribute__((ext_vector_type(8)));
typedef float  v4f32  __attribute__((ext_vector_type(4)));

static __device__ __forceinline__ float leaky(float v) { return v >= 0.0f ? v : 0.01f * v; }
static __device__ __forceinline__ float bfbits2f(unsigned short b) {
    union { unsigned u; float f; } c; c.u = ((unsigned)b) << 16; return c.f;
}
static __device__ __forceinline__ unsigned short f2bfbits(float f) {
    __hip_bfloat16 h = __float2bfloat16(f);
    unsigned short s; __builtin_memcpy(&s, &h, 2); return s;
}

// ---------------------------------------------------------------------------
// Weight transpose+cvt: W[K][N] fp32 -> Wt[N][K] bf16  (for small GEMMs)
// ---------------------------------------------------------------------------
__global__ void transpose_cvt(const float* __restrict__ W,
                              __hip_bfloat16* __restrict__ Wt, int K, int N) {
    int i = blockIdx.x * 256 + threadIdx.x;
    if (i >= K * N) return;
    int r = i / N, c = i % N;
    Wt[c * K + r] = __float2bfloat16(W[i]);
}

// ---------------------------------------------------------------------------
// W1 -> MFMA-fragment-ordered bf16 layout for gemm_enc1.
// Element tid: j=tid&7 (k-sub), l=(tid>>3)&63 (lane), G=tid>>9 (fragment,
// G = kk*8 + t). lane l=(q<<4)|m holds B[n=t*16+m][k=kk*32+q*8+j].
// W is [K=512][N=128] row-major.
// ---------------------------------------------------------------------------
__global__ void prep_frag(const float* __restrict__ W, __hip_bfloat16* __restrict__ out,
                          int K, int N, int total) {
    int tid = blockIdx.x * 256 + threadIdx.x;
    if (tid >= total) return;
    int j = tid & 7, l = (tid >> 3) & 63, G = tid >> 9;
    int m = l & 15, q = l >> 4;
    int t = G & 7, kk = G >> 3;
    int n = t * 16 + m;
    int k = kk * 32 + q * 8 + j;
    out[tid] = __float2bfloat16(W[k * N + n]);
}

// ---------------------------------------------------------------------------
// CSR build: histogram(+rank) -> scan -> atomic-free placement
// ---------------------------------------------------------------------------
__global__ void zero_u32(unsigned* __restrict__ p, int n) {
    int i = blockIdx.x * 256 + threadIdx.x;
    if (i < n) p[i] = 0u;
}
__global__ void deg_rank(const int* __restrict__ dst, unsigned* __restrict__ deg,
                         unsigned* __restrict__ rank, int E) {
    int e = blockIdx.x * 256 + threadIdx.x;
    if (e < E) rank[e] = atomicAdd(&deg[dst[e]], 1u);
}
__global__ void dinv_kernel(const unsigned* __restrict__ deg, float* __restrict__ dinv, int n) {
    int i = blockIdx.x * 256 + threadIdx.x;
    if (i < n) dinv[i] = rsqrtf((float)(deg[i] + 1u));  // +1 self-loop
}

__global__ __launch_bounds__(256) void scan1(const unsigned* __restrict__ in,
                                             unsigned* __restrict__ incl,
                                             unsigned* __restrict__ partials, int n) {
    __shared__ unsigned ts[256];
    const int tid = threadIdx.x;
    const int base = blockIdx.x * 1024 + tid * 4;
    unsigned v[4], s = 0;
#pragma unroll
    for (int j = 0; j < 4; j++) { v[j] = (base + j < n) ? in[base + j] : 0u; s += v[j]; }
    ts[tid] = s;
    __syncthreads();
    for (int off = 1; off < 256; off <<= 1) {
        unsigned t = (tid >= off) ? ts[tid - off] : 0u;
        __syncthreads();
        ts[tid] += t;
        __syncthreads();
    }
    unsigned run = ts[tid] - s;
#pragma unroll
    for (int j = 0; j < 4; j++) {
        run += v[j];
        if (base + j < n) incl[base + j] = run;
    }
    if (tid == 255) partials[blockIdx.x] = ts[255];
}

__global__ __launch_bounds__(128) void scan2(unsigned* __restrict__ partials, int nb) {
    __shared__ unsigned ts[128];
    const int tid = threadIdx.x;
    unsigned v = (tid < nb) ? partials[tid] : 0u;
    ts[tid] = v;
    __syncthreads();
    for (int off = 1; off < 128; off <<= 1) {
        unsigned t = (tid >= off) ? ts[tid - off] : 0u;
        __syncthreads();
        ts[tid] += t;
        __syncthreads();
    }
    if (tid < nb) partials[tid] = ts[tid] - v;
}

__global__ void scan3(const unsigned* __restrict__ incl, const unsigned* __restrict__ partials,
                      unsigned* __restrict__ rowptr, int n) {
    int i = blockIdx.x * 256 + threadIdx.x;
    if (i >= n) return;
    rowptr[i + 1] = incl[i] + partials[i >> 10];
    if (i == 0) rowptr[0] = 0u;
}

__global__ void fill_csr(const int* __restrict__ src, const int* __restrict__ dst,
                         const unsigned* __restrict__ rank, const unsigned* __restrict__ rowptr,
                         int* __restrict__ csr_src, int E) {
    int e = blockIdx.x * 256 + threadIdx.x;
    if (e >= E) return;
    csr_src[rowptr[dst[e]] + rank[e]] = src[e];
}

// ---------------------------------------------------------------------------
// GEMM1 (encoder layer 1): C[M,128] = leaky(A[M,512]@W1 + b1), A fp32.
// Block: 64 rows (4 waves x 16) x 128 cols. K chunked by 64, LDS dbuf.
// Bp is fragment-ordered (prep_frag): chunk c = uint4 [c*1024, c*1024+1024).
// Lane reads its B fragment at lds base + lane*16 (conflict-free, coalesced).
// A prefetched one chunk ahead in registers (4 dwordx4 in flight / lane).
// ---------------------------------------------------------------------------
__global__ __launch_bounds__(256, 4) void gemm_enc1(
    const float* __restrict__ A, const uint4* __restrict__ Bp,
    const float* __restrict__ bias, __hip_bfloat16* __restrict__ C, int M) {
    constexpr int K = 512;
    __shared__ uint4 lds[2][1024];  // 2 x 16 KB
    const int tid = threadIdx.x;
    const int wid = tid >> 6, lane = tid & 63;
    const int m = lane & 15, q = lane >> 4;
    const int row0 = blockIdx.x * 64 + wid * 16;
    const int rowA = row0 + m;
    const int rowAc = rowA < M ? rowA : M - 1;
    const float* Ap = A + (size_t)rowAc * K + q * 8;

    v4f32 acc[8];
#pragma unroll
    for (int t = 0; t < 8; t++) acc[t] = (v4f32){0.f, 0.f, 0.f, 0.f};

    float4 ab[2][4];  // [parity][kk2*2+half]

    auto loadA = [&](int c, int par) {
#pragma unroll
        for (int j = 0; j < 4; j++)
            ab[par][j] = *reinterpret_cast<const float4*>(Ap + c * 64 + (j >> 1) * 32 + (j & 1) * 4);
    };
    auto stage = [&](int c, int par) {
#pragma unroll
        for (int r = 0; r < 4; r++)
            lds[par][r * 256 + tid] = Bp[c * 1024 + r * 256 + tid];
    };

    stage(0, 0);
    loadA(0, 0);
    for (int c = 0; c < 8; c++) {
        __syncthreads();
        if (c < 7) { stage(c + 1, (c + 1) & 1); loadA(c + 1, (c + 1) & 1); }
        const int par = c & 1;
#pragma unroll
        for (int kk2 = 0; kk2 < 2; kk2++) {
            float4 f0 = ab[par][kk2 * 2], f1 = ab[par][kk2 * 2 + 1];
            v8bf16 a = {(__bf16)f0.x, (__bf16)f0.y, (__bf16)f0.z, (__bf16)f0.w,
                        (__bf16)f1.x, (__bf16)f1.y, (__bf16)f1.z, (__bf16)f1.w};
#pragma unroll
            for (int t = 0; t < 8; t++) {
                v8bf16 b = reinterpret_cast<const v8bf16*>(lds[par])[(kk2 * 8 + t) * 64 + lane];
                acc[t] = __builtin_amdgcn_mfma_f32_16x16x32_bf16(a, b, acc[t], 0, 0, 0);
            }
        }
    }

    // epilogue: D row = row0 + q*4 + r, col = t*16 + m
#pragma unroll
    for (int r = 0; r < 4; r++) {
        const int row = row0 + q * 4 + r;
        if (row >= M) continue;
#pragma unroll
        for (int t = 0; t < 8; t++) {
            const int col = t * 16 + m;
            C[(size_t)row * 128 + col] = __float2bfloat16(leaky(acc[t][r] + bias[col]));
        }
    }
}

// ---------------------------------------------------------------------------
// Small GEMM (bf16 A): C[M,N] = A[M,K]@B, Bt[N][K] bf16.
// MODE 0: C=bf16(leaky(AB+bias));  MODE 1: C=bf16((AB)*dinv[row])
// ---------------------------------------------------------------------------
template <int NT, int MODE>
__global__ __launch_bounds__(256) void gemm_kernel(
    const __hip_bfloat16* __restrict__ A, const __hip_bfloat16* __restrict__ Bt,
    const float* __restrict__ bias, const float* __restrict__ dinv,
    __hip_bfloat16* __restrict__ Cbf, int M, int K) {
    const int wid  = threadIdx.x >> 6;
    const int lane = threadIdx.x & 63;
    const int row0 = (blockIdx.x * 4 + wid) << 4;
    if (row0 >= M) return;
    const int m = lane & 15, q = lane >> 4;

    const __hip_bfloat16* Ab = A + (size_t)(row0 + m) * K + q * 8;

    v4f32 acc[NT];
#pragma unroll
    for (int t = 0; t < NT; t++) acc[t] = (v4f32){0.f, 0.f, 0.f, 0.f};

    for (int k0 = 0; k0 < K; k0 += 32) {
        v8bf16 a = *reinterpret_cast<const v8bf16*>(Ab + k0);
#pragma unroll
        for (int t = 0; t < NT; t++) {
            v8bf16 b = *reinterpret_cast<const v8bf16*>(Bt + (size_t)(t * 16 + m) * K + k0 + q * 8);
            acc[t] = __builtin_amdgcn_mfma_f32_16x16x32_bf16(a, b, acc[t], 0, 0, 0);
        }
    }

    const int N = NT * 16;
#pragma unroll
    for (int r = 0; r < 4; r++) {
        const int row = row0 + q * 4 + r;
        float di = (MODE == 1) ? dinv[row] : 1.0f;
#pragma unroll
        for (int t = 0; t < NT; t++) {
            const int col = t * 16 + m;
            float v = acc[t][r];
            if (MODE == 0) v = leaky(v + bias[col]);
            else           v *= di;
            Cbf[(size_t)row * N + col] = __float2bfloat16(v);
        }
    }
}

// ---------------------------------------------------------------------------
// Fused CSR gather + GCN epilogue. One wave per dst node.
// ---------------------------------------------------------------------------
template <int HEAD>
__global__ __launch_bounds__(256) void gather_kernel(
    const unsigned* __restrict__ rowptr, const int* __restrict__ csr_src,
    const __hip_bfloat16* __restrict__ u, const float* __restrict__ dinv,
    const float* __restrict__ bias, __hip_bfloat16* __restrict__ out_bf,
    float* __restrict__ out_h, const float* __restrict__ Wc,
    const float* __restrict__ bc, float* __restrict__ out_logits, int n) {
    const int node = blockIdx.x * 4 + (threadIdx.x >> 6);
    if (node >= n) return;
    const int lane = threadIdx.x & 63;
    const int g = lane >> 4, t = lane & 15;
    const unsigned beg = rowptr[node], end = rowptr[node + 1];

    float s0 = 0.f, s1 = 0.f, s2 = 0.f, s3 = 0.f;
    for (unsigned e = beg + g; e < end; e += 4) {
        int sidx = csr_src[e];
        ushort4 w = *reinterpret_cast<const ushort4*>(u + (size_t)sidx * 64 + t * 4);
        s0 += bfbits2f(w.x); s1 += bfbits2f(w.y); s2 += bfbits2f(w.z); s3 += bfbits2f(w.w);
    }
    s0 += __shfl_xor(s0, 16, 64); s1 += __shfl_xor(s1, 16, 64);
    s2 += __shfl_xor(s2, 16, 64); s3 += __shfl_xor(s3, 16, 64);
    s0 += __shfl_xor(s0, 32, 64); s1 += __shfl_xor(s1, 32, 64);
    s2 += __shfl_xor(s2, 32, 64); s3 += __shfl_xor(s3, 32, 64);

    ushort4 ws = *reinterpret_cast<const ushort4*>(u + (size_t)node * 64 + t * 4);
    s0 += bfbits2f(ws.x); s1 += bfbits2f(ws.y); s2 += bfbits2f(ws.z); s3 += bfbits2f(ws.w);

    const float di = dinv[node];
    const int f0i = t * 4;
    float f0 = leaky(s0 * di + bias[f0i + 0]);
    float f1 = leaky(s1 * di + bias[f0i + 1]);
    float f2 = leaky(s2 * di + bias[f0i + 2]);
    float f3 = leaky(s3 * di + bias[f0i + 3]);

    if (HEAD == 0) {
        if (g == 0) {
            ushort4 o = {f2bfbits(f0), f2bfbits(f1), f2bfbits(f2), f2bfbits(f3)};
            *reinterpret_cast<ushort4*>(out_bf + (size_t)node * 64 + f0i) = o;
        }
    } else {
        if (g == 0) {
            float4 o = {f0, f1, f2, f3};
            *reinterpret_cast<float4*>(out_h + (size_t)node * 64 + f0i) = o;
        }
        float p0 = f0 * Wc[(f0i + 0) * 2] + f1 * Wc[(f0i + 1) * 2] +
                   f2 * Wc[(f0i + 2) * 2] + f3 * Wc[(f0i + 3) * 2];
        float p1 = f0 * Wc[(f0i + 0) * 2 + 1] + f1 * Wc[(f0i + 1) * 2 + 1] +
                   f2 * Wc[(f0i + 2) * 2 + 1] + f3 * Wc[(f0i + 3) * 2 + 1];
#pragma unroll
        for (int o = 8; o; o >>= 1) {
            p0 += __shfl_xor(p0, o, 64);
            p1 += __shfl_xor(p1, o, 64);
        }
        if (lane == 0) {
            out_logits[(size_t)node * 2 + 0] = p0 + bc[0];
            out_logits[(size_t)node * 2 + 1] = p1 + bc[1];
        }
    }
}

// ---------------------------------------------------------------------------
extern "C" void kernel_launch(void* const* d_in, const int* in_sizes, int n_in,
                              void* d_out, int out_size, void* d_ws, size_t ws_size,
                              hipStream_t stream) {
    const float* x   = (const float*)d_in[0];
    const int*   ei  = (const int*)d_in[1];
    const float* W1  = (const float*)d_in[2];
    const float* b1  = (const float*)d_in[3];
    const float* W2  = (const float*)d_in[4];
    const float* b2  = (const float*)d_in[5];
    const float* Wg1 = (const float*)d_in[6];
    const float* bg1 = (const float*)d_in[7];
    const float* Wg2 = (const float*)d_in[8];
    const float* bg2 = (const float*)d_in[9];
    const float* Wc  = (const float*)d_in[10];
    const float* bc  = (const float*)d_in[11];

    const int DH  = in_sizes[3];            // 128
    const int DIN = in_sizes[2] / DH;       // 512
    const int NN  = in_sizes[0] / DIN;      // 100000
    const int E   = in_sizes[1] / 2;        // 3200000
    const int DO  = in_sizes[5];            // 64
    const int* src = ei;
    const int* dst = ei + E;

    // workspace layout (~92 MB total)
    char*  ws  = (char*)d_ws;
    size_t off = 0;
    auto alloc = [&](size_t bytes) {
        void* p = ws + off;
        off += (bytes + 255) & ~(size_t)255;
        return p;
    };
    __hip_bfloat16* h1    = (__hip_bfloat16*)alloc((size_t)NN * DH * 2);
    __hip_bfloat16* h2    = (__hip_bfloat16*)alloc((size_t)NN * DO * 2);
    __hip_bfloat16* h3    = (__hip_bfloat16*)alloc((size_t)NN * DO * 2);
    __hip_bfloat16* ub    = (__hip_bfloat16*)alloc((size_t)NN * DO * 2);
    unsigned*       deg   = (unsigned*)alloc((size_t)NN * 4);
    float*          dinv  = (float*)alloc((size_t)NN * 4);
    unsigned*       incl  = (unsigned*)alloc((size_t)NN * 4);
    unsigned*       parts = (unsigned*)alloc(128 * 4);
    unsigned*       rowp  = (unsigned*)alloc(((size_t)NN + 1) * 4);
    unsigned*       rank  = (unsigned*)alloc((size_t)E * 4);
    int*            csr   = (int*)alloc((size_t)E * 4);
    __hip_bfloat16* W1f   = (__hip_bfloat16*)alloc((size_t)DIN * DH * 2);  // fragment-ordered
    __hip_bfloat16* W2t   = (__hip_bfloat16*)alloc((size_t)DH * DO * 2);
    __hip_bfloat16* Wg1t  = (__hip_bfloat16*)alloc((size_t)DO * DO * 2);
    __hip_bfloat16* Wg2t  = (__hip_bfloat16*)alloc((size_t)DO * DO * 2);

    float* out_logits = (float*)d_out;
    float* out_h      = (float*)d_out + (size_t)NN * 2;

    // 1. weight prep
    prep_frag<<<(DIN * DH + 255) / 256, 256, 0, stream>>>(W1, W1f, DIN, DH, DIN * DH);
    transpose_cvt<<<(DH * DO + 255) / 256, 256, 0, stream>>>(W2, W2t, DH, DO);
    transpose_cvt<<<(DO * DO + 255) / 256, 256, 0, stream>>>(Wg1, Wg1t, DO, DO);
    transpose_cvt<<<(DO * DO + 255) / 256, 256, 0, stream>>>(Wg2, Wg2t, DO, DO);

    // 2. CSR build (shared by both GCN layers)
    zero_u32<<<(NN + 255) / 256, 256, 0, stream>>>(deg, NN);
    deg_rank<<<(E + 255) / 256, 256, 0, stream>>>(dst, deg, rank, E);
    dinv_kernel<<<(NN + 255) / 256, 256, 0, stream>>>(deg, dinv, NN);
    const int nb1 = (NN + 1023) / 1024;  // 98 <= 128
    scan1<<<nb1, 256, 0, stream>>>(deg, incl, parts, NN);
    scan2<<<1, 128, 0, stream>>>(parts, nb1);
    scan3<<<(NN + 255) / 256, 256, 0, stream>>>(incl, parts, rowp, NN);
    fill_csr<<<(E + 255) / 256, 256, 0, stream>>>(src, dst, rank, rowp, csr, E);

    const int gemm_blocks = (NN / 16 + 3) / 4;

    // 3. encoder
    gemm_enc1<<<(NN + 63) / 64, 256, 0, stream>>>(x, (const uint4*)W1f, b1, h1, NN);
    gemm_kernel<4, 0><<<gemm_blocks, 256, 0, stream>>>(h1, W2t, b2, nullptr, h2, NN, DH);

    // 4. GCN layer 1: u = (h2@Wg1)*dinv ; gather+epilogue -> h3 (bf16)
    gemm_kernel<4, 1><<<gemm_blocks, 256, 0, stream>>>(h2, Wg1t, nullptr, dinv, ub, NN, DO);
    gather_kernel<0><<<(NN + 3) / 4, 256, 0, stream>>>(rowp, csr, ub, dinv, bg1, h3,
                                                       nullptr, nullptr, nullptr, nullptr, NN);

    // 5. GCN layer 2 + head
    gemm_kernel<4, 1><<<gemm_blocks, 256, 0, stream>>>(h3, Wg2t, nullptr, dinv, ub, NN, DO);
    gather_kernel<1><<<(NN + 3) / 4, 256, 0, stream>>>(rowp, csr, ub, dinv, bg2, nullptr,
                                                       out_h, Wc, bc, out_logits, NN);
}